// Round 1
// baseline (4271.946 us; speedup 1.0000x reference)
//
#include <hip/hip_runtime.h>
#include <math.h>

// GaussianMixtureLayer: EM loop (<=8 iters, device-side convergence flag) +
// final update + Gaussian log-prob loss. All fp32, faithful to reference.
//
// Heavy kernels:
//   k_solve  : w[n,k] = || L_k^{-1} (x_n - m_k) ||^2   (forward substitution)
//   k_scatter: S_k = sum_n w x x^T                     (weighted syrk, 8x8 reg tiles)
// cov update: new_C = (S - m num^T - num m^T + sw m m^T)/sw + jitter*I  (old m)

#define NS 16384
#define DD 128
#define KC 16
#define JITTER_ 1e-6f
#define EPS2_ 1e-6f            // (1e-3)^2, Frobenius-norm convergence check
#define LOG_2PI_ 1.8378770664093454f

// workspace float offsets
enum : int {
  OFF_CUR_M  = 0,            // 16*128
  OFF_CUR_C  = 2048,         // 16*128*128
  OFF_LT     = 264192,       // L^T per k: LT[p][i] = L[i][p]
  OFF_INVD   = 526336,       // 1/L_ii
  OFF_LOGDET = 528384,       // 16
  OFF_W      = 528400,       // w[k][n], also reused for final mahalanobis
  OFF_SW     = 790544,       // 16
  OFF_NUM    = 790560,       // 16*128
  OFF_S      = 792608,       // 16*128*128
  OFF_DIFFSQ = 1054752,
  OFF_LOSS   = 1054753,
  OFF_DONE   = 1054754,      // int
  WS_FLOATS  = 1054756
};

// XOR-quad swizzle for 128x128 LDS matrix: rotates column quads by row index.
// Keeps float4 contiguity; makes lane-varying row accesses bank-conflict-free.
__device__ __forceinline__ int swz(int r, int c) {
  return (r << 7) + ((((c >> 2) + r) & 31) << 2) + (c & 3);
}

__global__ void k_init(const float* __restrict__ means, const float* __restrict__ covs,
                       float* __restrict__ ws) {
  int idx = blockIdx.x * blockDim.x + threadIdx.x;
  for (int i = idx; i < KC * DD * DD; i += gridDim.x * blockDim.x)
    ws[OFF_CUR_C + i] = covs[i];
  if (idx < KC * DD) ws[OFF_CUR_M + idx] = means[idx];
  if (idx == 0) {
    ws[OFF_DIFFSQ] = 0.f;
    ws[OFF_LOSS]   = 0.f;
    ((int*)ws)[OFF_DONE] = 0;
  }
}

// Blocked right-looking Cholesky of cur_C[k] in LDS (panel=32). Writes LT,
// 1/diag, optional logdet. Also zeroes this step's accumulators (S, num, sw).
__global__ __launch_bounds__(256) void k_chol(float* __restrict__ ws, int guarded, int final_pass) {
  if (guarded && ((const int*)ws)[OFF_DONE]) return;
  __shared__ float m[DD * DD];   // 64 KB, swizzled
  int k = blockIdx.x, t = threadIdx.x;
  const float* __restrict__ C = ws + OFF_CUR_C + k * DD * DD;
  for (int i = t; i < DD * DD; i += 256)
    m[swz(i >> 7, i & 127)] = C[i];
  float* __restrict__ Sz = ws + OFF_S + k * DD * DD;
  for (int i = t; i < DD * DD; i += 256) Sz[i] = 0.f;
  if (t < DD) ws[OFF_NUM + k * DD + t] = 0.f;
  if (t == 0) ws[OFF_SW + k] = 0.f;
  __syncthreads();

  for (int P = 0; P < DD; P += 32) {
    bool rowAct = (t >= P) && (t < DD);
    float r[32];   // this thread's row, panel segment (register-cached)
    if (rowAct) {
      #pragma unroll
      for (int q = 0; q < 8; ++q) {
        float4 v = *(const float4*)&m[swz(t, P + 4 * q)];
        r[4*q+0] = v.x; r[4*q+1] = v.y; r[4*q+2] = v.z; r[4*q+3] = v.w;
      }
    }
    // panel factorization, left-looking with register rows; pivot row broadcast via LDS
    #pragma unroll
    for (int jj = 0; jj < 32; ++jj) {
      int j = P + jj;
      if (t == j) {
        float dsum = 0.f;
        #pragma unroll
        for (int p = 0; p < jj; ++p) dsum += r[p] * r[p];
        r[jj] = sqrtf(r[jj] - dsum);
        #pragma unroll
        for (int q = 0; q < 8; ++q) {
          if (4 * q <= jj)
            *(float4*)&m[swz(j, P + 4 * q)] = make_float4(r[4*q], r[4*q+1], r[4*q+2], r[4*q+3]);
        }
      }
      __syncthreads();
      if (t > j && t < DD) {
        float rj[32];
        #pragma unroll
        for (int q = 0; q < 8; ++q) {
          if (4 * q <= jj) {
            float4 v = *(const float4*)&m[swz(j, P + 4 * q)];
            rj[4*q+0] = v.x; rj[4*q+1] = v.y; rj[4*q+2] = v.z; rj[4*q+3] = v.w;
          }
        }
        float dsum = 0.f;
        #pragma unroll
        for (int p = 0; p < jj; ++p) dsum += r[p] * rj[p];
        r[jj] = (r[jj] - dsum) / rj[jj];
      }
    }
    __syncthreads();
    if (rowAct) {
      #pragma unroll
      for (int q = 0; q < 8; ++q)
        *(float4*)&m[swz(t, P + 4 * q)] = make_float4(r[4*q], r[4*q+1], r[4*q+2], r[4*q+3]);
    }
    __syncthreads();
    // trailing update: C[i][q] -= sum_{p in panel} L[i][p] L[q][p]
    int R0 = P + 32;
    if (R0 < DD) {
      int s = DD - R0;
      int tq = R0 + (t & 31);
      for (int b = 0; b < s; b += 32) {
        int q = tq + b;
        float lq[32];
        #pragma unroll
        for (int p4 = 0; p4 < 8; ++p4) {
          float4 v = *(const float4*)&m[swz(q, P + 4 * p4)];
          lq[4*p4+0] = v.x; lq[4*p4+1] = v.y; lq[4*p4+2] = v.z; lq[4*p4+3] = v.w;
        }
        for (int i = R0 + (t >> 5); i < DD; i += 8) {
          float a = m[swz(i, q)];
          #pragma unroll
          for (int p4 = 0; p4 < 8; ++p4) {
            float4 v = *(const float4*)&m[swz(i, P + 4 * p4)];
            a -= v.x * lq[4*p4+0] + v.y * lq[4*p4+1] + v.z * lq[4*p4+2] + v.w * lq[4*p4+3];
          }
          m[swz(i, q)] = a;
        }
      }
    }
    __syncthreads();
  }

  float* __restrict__ LT = ws + OFF_LT + k * DD * DD;   // LT[p][i] = L[i][p]
  for (int idx = t; idx < DD * DD; idx += 256) {
    int p = idx >> 7, i = idx & 127;
    LT[idx] = (i >= p) ? m[swz(i, p)] : 0.f;
  }
  if (t < DD) ws[OFF_INVD + k * DD + t] = 1.f / m[swz(t, t)];
  if (final_pass && t == 0) {
    float ld = 0.f;
    for (int i = 0; i < DD; ++i) ld += logf(m[swz(i, i)]);
    ws[OFF_LOGDET + k] = 2.f * ld;
    if (k == 0) ws[OFF_LOSS] = 0.f;
  }
}

// w[n,k] = ||L^{-1}(x-m)||^2 via forward substitution, 64 samples/wave.
// y history in LDS (lane-indexed, conflict-free); L rows wave-uniform -> s_loads.
__global__ __launch_bounds__(64) void k_solve(const float* __restrict__ x,
                                              float* __restrict__ ws, int guarded) {
  if (guarded && ((const int*)ws)[OFF_DONE]) return;
  __shared__ float y[DD * 64];   // y[p][lane], 32 KB
  int lane = threadIdx.x;
  int k = blockIdx.y;
  int n = blockIdx.x * 64 + lane;
  const float* __restrict__ LT   = ws + OFF_LT   + k * DD * DD;
  const float* __restrict__ mm   = ws + OFF_CUR_M + k * DD;
  const float* __restrict__ invd = ws + OFF_INVD + k * DD;
  const float* __restrict__ xrow = x + (size_t)n * DD;
  float wacc = 0.f;
  #pragma unroll 1
  for (int t4 = 0; t4 < 4; ++t4) {
    int i0 = t4 * 32;
    float xr[32];
    #pragma unroll
    for (int q = 0; q < 8; ++q) {
      float4 v = *(const float4*)(xrow + i0 + 4 * q);
      xr[4*q+0] = v.x; xr[4*q+1] = v.y; xr[4*q+2] = v.z; xr[4*q+3] = v.w;
    }
    float acc[32];
    #pragma unroll
    for (int ii = 0; ii < 32; ++ii) acc[ii] = 0.f;
    for (int p = 0; p < i0; ++p) {          // GEMV vs earlier y
      float yv = y[p * 64 + lane];
      const float* __restrict__ Lp = LT + p * DD + i0;   // contiguous, uniform
      #pragma unroll
      for (int ii = 0; ii < 32; ++ii) acc[ii] += Lp[ii] * yv;
    }
    #pragma unroll
    for (int jj = 0; jj < 32; ++jj) {       // diagonal 32x32 triangle
      float rhs = xr[jj] - mm[i0 + jj] - acc[jj];
      float yi = rhs * invd[i0 + jj];
      wacc += yi * yi;
      y[(i0 + jj) * 64 + lane] = yi;
      const float* __restrict__ Li = LT + (i0 + jj) * DD + i0;
      #pragma unroll
      for (int jj2 = jj + 1; jj2 < 32; ++jj2) acc[jj2] += Li[jj2] * yi;
    }
  }
  ws[OFF_W + k * NS + n] = wacc;
}

// num[k][d] = sum_n w x[n][d]; sw[k] = sum_n w   (split-N, atomics)
__global__ __launch_bounds__(128) void k_reduce(const float* __restrict__ x,
                                                float* __restrict__ ws, int guarded) {
  if (guarded && ((const int*)ws)[OFF_DONE]) return;
  int k = blockIdx.y, chunk = blockIdx.x, t = threadIdx.x;
  const float* __restrict__ wv = ws + OFF_W + k * NS + chunk * 512;
  float accn = 0.f, accs = 0.f;
  for (int j = 0; j < 512; ++j) {
    float wn = wv[j];               // wave-uniform
    accs += wn;
    accn += wn * x[(size_t)(chunk * 512 + j) * DD + t];
  }
  atomicAdd(&ws[OFF_NUM + k * DD + t], accn);
  if (t == 0) atomicAdd(&ws[OFF_SW + k], accs);
}

// S[k] += sum_n w x x^T over a 512-sample chunk; 8x8 register tiles from LDS.
__global__ __launch_bounds__(256) void k_scatter(const float* __restrict__ x,
                                                 float* __restrict__ ws, int guarded) {
  if (guarded && ((const int*)ws)[OFF_DONE]) return;
  __shared__ float xs[64 * 132];   // pad 132 vs bank conflicts
  __shared__ float wls[64];
  int k = blockIdx.y, chunk = blockIdx.x, t = threadIdx.x;
  int d0 = (t >> 4) * 8, e0 = (t & 15) * 8;
  float acc[8][8];
  #pragma unroll
  for (int a = 0; a < 8; ++a)
    #pragma unroll
    for (int b = 0; b < 8; ++b) acc[a][b] = 0.f;
  for (int sub = 0; sub < 8; ++sub) {
    int n0 = chunk * 512 + sub * 64;
    __syncthreads();
    for (int idx = t; idx < 2048; idx += 256) {
      int rr = idx >> 5, qq = idx & 31;
      *(float4*)&xs[rr * 132 + qq * 4] = *(const float4*)(x + (size_t)(n0 + rr) * DD + qq * 4);
    }
    if (t < 64) wls[t] = ws[OFF_W + k * NS + n0 + t];
    __syncthreads();
    for (int n = 0; n < 64; ++n) {
      float wn = wls[n];
      float4 a0 = *(const float4*)&xs[n * 132 + d0];
      float4 a1 = *(const float4*)&xs[n * 132 + d0 + 4];
      float4 b0 = *(const float4*)&xs[n * 132 + e0];
      float4 b1 = *(const float4*)&xs[n * 132 + e0 + 4];
      float av[8] = {a0.x*wn, a0.y*wn, a0.z*wn, a0.w*wn, a1.x*wn, a1.y*wn, a1.z*wn, a1.w*wn};
      float bv[8] = {b0.x, b0.y, b0.z, b0.w, b1.x, b1.y, b1.z, b1.w};
      #pragma unroll
      for (int a = 0; a < 8; ++a)
        #pragma unroll
        for (int b = 0; b < 8; ++b) acc[a][b] += av[a] * bv[b];
    }
  }
  float* __restrict__ Sg = ws + OFF_S + k * DD * DD;
  #pragma unroll
  for (int a = 0; a < 8; ++a)
    #pragma unroll
    for (int b = 0; b < 8; ++b)
      atomicAdd(&Sg[(d0 + a) * DD + (e0 + b)], acc[a][b]);
}

// new_m = num/sw; new_C = (S - m num^T - num m^T + sw m m^T)/sw + jitter*I (old m).
__global__ __launch_bounds__(128) void k_update(float* __restrict__ ws, float* __restrict__ dout,
                                                int guarded, int write_out, int accum_diff) {
  if (guarded && ((const int*)ws)[OFF_DONE]) return;
  __shared__ float red[128];
  int k = blockIdx.x, e = threadIdx.x;
  float sw = ws[OFF_SW + k];
  float inv = 1.f / sw;
  float me = ws[OFF_CUR_M + k * DD + e];
  float ne = ws[OFF_NUM + k * DD + e];
  const float* __restrict__ S  = ws + OFF_S + k * DD * DD;
  float* __restrict__ Cv = ws + OFF_CUR_C + k * DD * DD;
  const float* __restrict__ cm = ws + OFF_CUR_M + k * DD;
  const float* __restrict__ nm = ws + OFF_NUM + k * DD;
  for (int d = 0; d < DD; ++d) {
    float md = cm[d];
    float nd = nm[d];
    float v = (S[d * DD + e] - md * ne - nd * me + sw * md * me) * inv;
    if (d == e) v += JITTER_;
    Cv[d * DD + e] = v;
    if (write_out) dout[1 + KC * DD + k * DD * DD + d * DD + e] = v;
  }
  __syncthreads();
  float newm = ne * inv;
  ws[OFF_CUR_M + k * DD + e] = newm;
  if (write_out) dout[1 + k * DD + e] = newm;
  if (accum_diff) {
    float dm = newm - me;
    red[e] = dm * dm;
    __syncthreads();
    for (int s2 = 64; s2 > 0; s2 >>= 1) {
      if (e < s2) red[e] += red[e + s2];
      __syncthreads();
    }
    if (e == 0) atomicAdd(&ws[OFF_DIFFSQ], red[0]);
  }
}

__global__ void k_flag(float* __restrict__ ws) {
  if (threadIdx.x == 0) {
    int* done = (int*)ws + OFF_DONE;
    if (!*done && ws[OFF_DIFFSQ] <= EPS2_) *done = 1;
    ws[OFF_DIFFSQ] = 0.f;
  }
}

__global__ __launch_bounds__(256) void k_lossred(const float* __restrict__ weights,
                                                 float* __restrict__ ws) {
  __shared__ float red[256];
  int k = blockIdx.y, chunk = blockIdx.x, t = threadIdx.x;
  const float* __restrict__ mh = ws + OFF_W + k * NS + chunk * 2048;
  float s = 0.f;
  for (int j = t; j < 2048; j += 256) s += mh[j];
  red[t] = s;
  __syncthreads();
  for (int s2 = 128; s2 > 0; s2 >>= 1) {
    if (t < s2) red[t] += red[t + s2];
    __syncthreads();
  }
  if (t == 0) atomicAdd(&ws[OFF_LOSS], 0.5f * weights[k] * red[0]);
}

__global__ void k_lossfin(const float* __restrict__ weights, const float* __restrict__ ws,
                          float* __restrict__ dout) {
  if (threadIdx.x == 0 && blockIdx.x == 0) {
    float base = 0.f;
    for (int k = 0; k < KC; ++k)
      base += weights[k] * 0.5f * (float)NS * ((float)DD * LOG_2PI_ + ws[OFF_LOGDET + k]);
    dout[0] = base + ws[OFF_LOSS];
  }
}

extern "C" void kernel_launch(void* const* d_in, const int* in_sizes, int n_in,
                              void* d_out, int out_size, void* d_ws, size_t ws_size,
                              hipStream_t stream) {
  const float* x       = (const float*)d_in[0];
  const float* means   = (const float*)d_in[1];
  const float* covs    = (const float*)d_in[2];
  const float* weights = (const float*)d_in[3];
  float* out = (float*)d_out;
  float* ws  = (float*)d_ws;

  hipLaunchKernelGGL(k_init, dim3(256), dim3(256), 0, stream, means, covs, ws);

  // 8 guarded loop iterations + 1 unguarded final update (u==8)
  for (int u = 0; u < 9; ++u) {
    int guarded = (u < 8) ? 1 : 0;
    hipLaunchKernelGGL(k_chol,    dim3(16),      dim3(256), 0, stream, ws, guarded, 0);
    hipLaunchKernelGGL(k_solve,   dim3(256, 16), dim3(64),  0, stream, x, ws, guarded);
    hipLaunchKernelGGL(k_reduce,  dim3(32, 16),  dim3(128), 0, stream, x, ws, guarded);
    hipLaunchKernelGGL(k_scatter, dim3(32, 16),  dim3(256), 0, stream, x, ws, guarded);
    hipLaunchKernelGGL(k_update,  dim3(16),      dim3(128), 0, stream, ws, out, guarded,
                       (u == 8) ? 1 : 0, guarded);
    if (u < 8) hipLaunchKernelGGL(k_flag, dim3(1), dim3(64), 0, stream, ws);
  }

  // final log-prob: Cholesky of c_fin (+logdet), mahalanobis, weighted loss
  hipLaunchKernelGGL(k_chol,    dim3(16),      dim3(256), 0, stream, ws, 0, 1);
  hipLaunchKernelGGL(k_solve,   dim3(256, 16), dim3(64),  0, stream, x, ws, 0);
  hipLaunchKernelGGL(k_lossred, dim3(8, 16),   dim3(256), 0, stream, weights, ws);
  hipLaunchKernelGGL(k_lossfin, dim3(1),       dim3(64),  0, stream, weights, ws, out);
}

// Round 2
// 3177.405 us; speedup vs baseline: 1.3445x; 1.3445x over previous
//
#include <hip/hip_runtime.h>
#include <math.h>

// GaussianMixtureLayer: EM loop (<=8 iters, device-side convergence flag) +
// final update + Gaussian log-prob loss. All fp32, faithful to reference.
//
// Heavy kernels (both GEMM-shaped, 8x8 register tiles):
//   k_quad   : w[n,k] = ||Linv_k x_n - t_k||^2  (GEMM + fused epilogue; also
//              accumulates num[k][d] = sum_n w x and sw[k] = sum_n w)
//   k_scatter: S_k = sum_n w x x^T              (weighted syrk)
// k_trinv: Linv = L^{-1} per component (column-per-thread, full unroll,
//          wave-uniform L reads -> scalar loads), plus t_k = Linv m_k.
// cov update: new_C = (S - m num^T - num m^T + sw m m^T)/sw + jitter*I (old m)

#define NS 16384
#define DD 128
#define KC 16
#define JITTER_ 1e-6f
#define EPS2_ 1e-6f            // (1e-3)^2, Frobenius-norm convergence check
#define LOG_2PI_ 1.8378770664093454f

// workspace float offsets. C and S share storage (OFF_CS): k_chol stages C
// into LDS then zeroes the region for this iteration's S accumulation;
// k_update rebuilds C from S in place.
enum : int {
  OFF_CUR_M  = 0,            // 16*128
  OFF_CS     = 2048,         // 16*128*128  (C, then S, then new C)
  OFF_LT     = 264192,       // L^T per k: LT[p][i] = L[i][p]
  OFF_LINVT  = 526336,       // LinvT[e][d] = Linv[d][e]
  OFF_INVD   = 788480,       // 1/L_ii
  OFF_T      = 790528,       // t_k = Linv_k m_k
  OFF_LOGDET = 792576,       // 16
  OFF_SW     = 792592,       // 16
  OFF_NUM    = 792608,       // 16*128
  OFF_W      = 794656,       // w[k][n], also final mahalanobis
  OFF_DIFFSQ = 1056800,
  OFF_LOSS   = 1056801,
  OFF_DONE   = 1056802,      // int
  WS_FLOATS  = 1056804
};

// XOR-quad swizzle for 128x128 LDS matrix: rotates column quads by row index.
__device__ __forceinline__ int swz(int r, int c) {
  return (r << 7) + ((((c >> 2) + r) & 31) << 2) + (c & 3);
}

__global__ void k_init(const float* __restrict__ means, const float* __restrict__ covs,
                       float* __restrict__ ws) {
  int idx = blockIdx.x * blockDim.x + threadIdx.x;
  for (int i = idx; i < KC * DD * DD; i += gridDim.x * blockDim.x)
    ws[OFF_CS + i] = covs[i];
  if (idx < KC * DD) ws[OFF_CUR_M + idx] = means[idx];
  if (idx == 0) {
    ws[OFF_DIFFSQ] = 0.f;
    ws[OFF_LOSS]   = 0.f;
    ((int*)ws)[OFF_DONE] = 0;
  }
}

// Blocked right-looking Cholesky of C[k] (from OFF_CS) in LDS (panel=32).
// Writes LT + 1/diag (+logdet on final pass), zeroes CS/num/sw accumulators.
__global__ __launch_bounds__(256) void k_chol(float* __restrict__ ws, int guarded, int final_pass) {
  if (guarded && ((const int*)ws)[OFF_DONE]) return;
  __shared__ float m[DD * DD];   // 64 KB, swizzled
  int k = blockIdx.x, t = threadIdx.x;
  float* __restrict__ C = ws + OFF_CS + (size_t)k * DD * DD;
  for (int i = t; i < DD * DD; i += 256) {
    m[swz(i >> 7, i & 127)] = C[i];
    C[i] = 0.f;                      // becomes this iteration's S accumulator
  }
  if (t < DD) ws[OFF_NUM + k * DD + t] = 0.f;
  if (t == 0) ws[OFF_SW + k] = 0.f;
  __syncthreads();

  for (int P = 0; P < DD; P += 32) {
    bool rowAct = (t >= P) && (t < DD);
    float r[32];
    if (rowAct) {
      #pragma unroll
      for (int q = 0; q < 8; ++q) {
        float4 v = *(const float4*)&m[swz(t, P + 4 * q)];
        r[4*q+0] = v.x; r[4*q+1] = v.y; r[4*q+2] = v.z; r[4*q+3] = v.w;
      }
    }
    #pragma unroll
    for (int jj = 0; jj < 32; ++jj) {
      int j = P + jj;
      if (t == j) {
        float dsum = 0.f;
        #pragma unroll
        for (int p = 0; p < jj; ++p) dsum += r[p] * r[p];
        r[jj] = sqrtf(r[jj] - dsum);
        #pragma unroll
        for (int q = 0; q < 8; ++q) {
          if (4 * q <= jj)
            *(float4*)&m[swz(j, P + 4 * q)] = make_float4(r[4*q], r[4*q+1], r[4*q+2], r[4*q+3]);
        }
      }
      __syncthreads();
      if (t > j && t < DD) {
        float rj[32];
        #pragma unroll
        for (int q = 0; q < 8; ++q) {
          if (4 * q <= jj) {
            float4 v = *(const float4*)&m[swz(j, P + 4 * q)];
            rj[4*q+0] = v.x; rj[4*q+1] = v.y; rj[4*q+2] = v.z; rj[4*q+3] = v.w;
          }
        }
        float dsum = 0.f;
        #pragma unroll
        for (int p = 0; p < jj; ++p) dsum += r[p] * rj[p];
        r[jj] = (r[jj] - dsum) / rj[jj];
      }
    }
    __syncthreads();
    if (rowAct) {
      #pragma unroll
      for (int q = 0; q < 8; ++q)
        *(float4*)&m[swz(t, P + 4 * q)] = make_float4(r[4*q], r[4*q+1], r[4*q+2], r[4*q+3]);
    }
    __syncthreads();
    int R0 = P + 32;
    if (R0 < DD) {
      int s = DD - R0;
      int tq = R0 + (t & 31);
      for (int b = 0; b < s; b += 32) {
        int q = tq + b;
        float lq[32];
        #pragma unroll
        for (int p4 = 0; p4 < 8; ++p4) {
          float4 v = *(const float4*)&m[swz(q, P + 4 * p4)];
          lq[4*p4+0] = v.x; lq[4*p4+1] = v.y; lq[4*p4+2] = v.z; lq[4*p4+3] = v.w;
        }
        for (int i = R0 + (t >> 5); i < DD; i += 8) {
          float a = m[swz(i, q)];
          #pragma unroll
          for (int p4 = 0; p4 < 8; ++p4) {
            float4 v = *(const float4*)&m[swz(i, P + 4 * p4)];
            a -= v.x * lq[4*p4+0] + v.y * lq[4*p4+1] + v.z * lq[4*p4+2] + v.w * lq[4*p4+3];
          }
          m[swz(i, q)] = a;
        }
      }
    }
    __syncthreads();
  }

  float* __restrict__ LT = ws + OFF_LT + (size_t)k * DD * DD;   // LT[p][i] = L[i][p]
  for (int idx = t; idx < DD * DD; idx += 256) {
    int p = idx >> 7, i = idx & 127;
    LT[idx] = (i >= p) ? m[swz(i, p)] : 0.f;
  }
  if (t < DD) ws[OFF_INVD + k * DD + t] = 1.f / m[swz(t, t)];
  if (final_pass && t == 0) {
    float ld = 0.f;
    for (int i = 0; i < DD; ++i) ld += logf(m[swz(i, i)]);
    ws[OFF_LOGDET + k] = 2.f * ld;
    if (k == 0) ws[OFF_LOSS] = 0.f;
  }
}

// Linv = L^{-1} per k: thread j owns column j (solve L z = e_j, right-looking,
// column in registers via full unroll). L reads are wave-uniform -> scalar
// loads. Writes LinvT[e][d] = Linv[d][e] (coalesced via LDS transpose) and
// t[d] = sum_e Linv[d][e] m[e].
__global__ __launch_bounds__(128) void k_trinv(float* __restrict__ ws, int guarded) {
  if (guarded && ((const int*)ws)[OFF_DONE]) return;
  __shared__ float Zs[DD * 129];   // Zs[j][i] = Linv[i][j]
  int k = blockIdx.x, j = threadIdx.x;
  const float* __restrict__ LT   = ws + OFF_LT + (size_t)k * DD * DD;
  const float* __restrict__ invd = ws + OFF_INVD + k * DD;
  float acc[DD];
  #pragma unroll
  for (int i = 0; i < DD; ++i) acc[i] = 0.f;
  #pragma unroll
  for (int p = 0; p < DD; ++p) {
    float zp = ((p == j) ? 1.f : 0.f) - acc[p];
    zp *= invd[p];                 // zero for p<j automatically
    Zs[j * 129 + p] = zp;
    #pragma unroll
    for (int i = p + 1; i < DD; ++i) acc[i] += LT[p * DD + i] * zp;
  }
  __syncthreads();
  float* __restrict__ LI = ws + OFF_LINVT + (size_t)k * DD * DD;
  for (int idx = j; idx < DD * DD; idx += 128)
    LI[idx] = Zs[(idx >> 7) * 129 + (idx & 127)];
  // t[j] = sum_e Linv[j][e] m[e] = sum_e Zs[e][j] m[e]
  const float* __restrict__ mk = ws + OFF_CUR_M + k * DD;
  float s0 = 0.f, s1 = 0.f, s2 = 0.f, s3 = 0.f;
  for (int e = 0; e < DD; e += 4) {
    s0 += Zs[(e + 0) * 129 + j] * mk[e + 0];
    s1 += Zs[(e + 1) * 129 + j] * mk[e + 1];
    s2 += Zs[(e + 2) * 129 + j] * mk[e + 2];
    s3 += Zs[(e + 3) * 129 + j] * mk[e + 3];
  }
  ws[OFF_T + k * DD + j] = (s0 + s1) + (s2 + s3);
}

// w[n,k] = ||Linv x_n - t||^2 as tiled GEMM (128n x 128d per block) with
// fused epilogue; also accumulates num[k][d] and sw[k].
__global__ __launch_bounds__(256) void k_quad(const float* __restrict__ x,
                                              float* __restrict__ ws, int guarded) {
  if (guarded && ((const int*)ws)[OFF_DONE]) return;
  __shared__ float smem[32 * 132 + 32 * 128];
  float* xs = smem;              // [e][n] 32 x 132 (transposed X chunk)
  float* bl = smem + 32 * 132;   // [e][d] 32 x 128 (LinvT chunk)
  int k = blockIdx.y;
  int n0 = blockIdx.x * 128;
  int t = threadIdx.x;
  int nb = (t >> 4) * 8, db = (t & 15) * 8;
  const float* __restrict__ LI = ws + OFF_LINVT + (size_t)k * DD * DD;
  float acc[8][8];
  #pragma unroll
  for (int a = 0; a < 8; ++a)
    #pragma unroll
    for (int b = 0; b < 8; ++b) acc[a][b] = 0.f;

  for (int ec = 0; ec < 4; ++ec) {
    __syncthreads();
    for (int fi = t; fi < 1024; fi += 256) {     // X chunk, transposed store
      int n = fi >> 3, q = fi & 7;
      float4 v = *(const float4*)(x + (size_t)(n0 + n) * DD + ec * 32 + q * 4);
      xs[(q * 4 + 0) * 132 + n] = v.x;
      xs[(q * 4 + 1) * 132 + n] = v.y;
      xs[(q * 4 + 2) * 132 + n] = v.z;
      xs[(q * 4 + 3) * 132 + n] = v.w;
    }
    for (int fi = t; fi < 1024; fi += 256) {     // LinvT chunk
      int e = fi >> 5, q = fi & 31;
      *(float4*)&bl[e * 128 + q * 4] =
          *(const float4*)(LI + (size_t)(ec * 32 + e) * DD + q * 4);
    }
    __syncthreads();
    #pragma unroll 4
    for (int e = 0; e < 32; ++e) {
      float4 a0 = *(const float4*)&xs[e * 132 + nb];
      float4 a1 = *(const float4*)&xs[e * 132 + nb + 4];
      float4 b0 = *(const float4*)&bl[e * 128 + db];
      float4 b1 = *(const float4*)&bl[e * 128 + db + 4];
      float av[8] = {a0.x,a0.y,a0.z,a0.w,a1.x,a1.y,a1.z,a1.w};
      float bv[8] = {b0.x,b0.y,b0.z,b0.w,b1.x,b1.y,b1.z,b1.w};
      #pragma unroll
      for (int a = 0; a < 8; ++a)
        #pragma unroll
        for (int b = 0; b < 8; ++b) acc[a][b] += av[a] * bv[b];
    }
  }

  // epilogue: per-thread squared distance over its 8 d's
  float tv[8];
  const float* __restrict__ tk = ws + OFF_T + k * DD + db;
  #pragma unroll
  for (int b = 0; b < 8; ++b) tv[b] = tk[b];
  float part[8];
  #pragma unroll
  for (int a = 0; a < 8; ++a) {
    float s = 0.f;
    #pragma unroll
    for (int b = 0; b < 8; ++b) {
      float d = acc[a][b] - tv[b];
      s += d * d;
    }
    part[a] = s;
  }
  __syncthreads();
  float* wred = smem;              // 128 x 17
  float* warr = smem + 32 * 132;   // 128
  #pragma unroll
  for (int a = 0; a < 8; ++a) wred[(nb + a) * 17 + (t & 15)] = part[a];
  __syncthreads();
  if (t < 128) {
    float s = 0.f;
    #pragma unroll
    for (int g = 0; g < 16; ++g) s += wred[t * 17 + g];
    warr[t] = s;
    ws[OFF_W + k * NS + n0 + t] = s;
  }
  __syncthreads();
  if (t < 128) {
    // num[k][d] += sum_n w[n] x[n][d]  (x rows are L1-hot from staging)
    float s = 0.f;
    for (int n = 0; n < 128; ++n) s += warr[n] * x[(size_t)(n0 + n) * DD + t];
    atomicAdd(&ws[OFF_NUM + k * DD + t], s);
  } else if (t == 128) {
    float s = 0.f;
    for (int n = 0; n < 128; ++n) s += warr[n];
    atomicAdd(&ws[OFF_SW + k], s);
  }
}

// S[k] += sum_n w x x^T over a 512-sample chunk; 8x8 register tiles from LDS.
__global__ __launch_bounds__(256) void k_scatter(const float* __restrict__ x,
                                                 float* __restrict__ ws, int guarded) {
  if (guarded && ((const int*)ws)[OFF_DONE]) return;
  __shared__ float xs[64 * 132];
  __shared__ float wls[64];
  int k = blockIdx.y, chunk = blockIdx.x, t = threadIdx.x;
  int d0 = (t >> 4) * 8, e0 = (t & 15) * 8;
  float acc[8][8];
  #pragma unroll
  for (int a = 0; a < 8; ++a)
    #pragma unroll
    for (int b = 0; b < 8; ++b) acc[a][b] = 0.f;
  for (int sub = 0; sub < 8; ++sub) {
    int n0 = chunk * 512 + sub * 64;
    __syncthreads();
    for (int idx = t; idx < 2048; idx += 256) {
      int rr = idx >> 5, qq = idx & 31;
      *(float4*)&xs[rr * 132 + qq * 4] = *(const float4*)(x + (size_t)(n0 + rr) * DD + qq * 4);
    }
    if (t < 64) wls[t] = ws[OFF_W + k * NS + n0 + t];
    __syncthreads();
    for (int n = 0; n < 64; ++n) {
      float wn = wls[n];
      float4 a0 = *(const float4*)&xs[n * 132 + d0];
      float4 a1 = *(const float4*)&xs[n * 132 + d0 + 4];
      float4 b0 = *(const float4*)&xs[n * 132 + e0];
      float4 b1 = *(const float4*)&xs[n * 132 + e0 + 4];
      float av[8] = {a0.x*wn, a0.y*wn, a0.z*wn, a0.w*wn, a1.x*wn, a1.y*wn, a1.z*wn, a1.w*wn};
      float bv[8] = {b0.x, b0.y, b0.z, b0.w, b1.x, b1.y, b1.z, b1.w};
      #pragma unroll
      for (int a = 0; a < 8; ++a)
        #pragma unroll
        for (int b = 0; b < 8; ++b) acc[a][b] += av[a] * bv[b];
    }
  }
  float* __restrict__ Sg = ws + OFF_CS + (size_t)k * DD * DD;
  #pragma unroll
  for (int a = 0; a < 8; ++a)
    #pragma unroll
    for (int b = 0; b < 8; ++b)
      atomicAdd(&Sg[(d0 + a) * DD + (e0 + b)], acc[a][b]);
}

// new_m = num/sw; new_C = (S - m num^T - num m^T + sw m m^T)/sw + jitter*I,
// in place over S (old m throughout).
__global__ __launch_bounds__(128) void k_update(float* __restrict__ ws, float* __restrict__ dout,
                                                int guarded, int write_out, int accum_diff) {
  if (guarded && ((const int*)ws)[OFF_DONE]) return;
  __shared__ float red[128];
  int k = blockIdx.x, e = threadIdx.x;
  float sw = ws[OFF_SW + k];
  float inv = 1.f / sw;
  float me = ws[OFF_CUR_M + k * DD + e];
  float ne = ws[OFF_NUM + k * DD + e];
  float* __restrict__ SC = ws + OFF_CS + (size_t)k * DD * DD;
  const float* __restrict__ cm = ws + OFF_CUR_M + k * DD;
  const float* __restrict__ nm = ws + OFF_NUM + k * DD;
  for (int d = 0; d < DD; ++d) {
    float md = cm[d];
    float nd = nm[d];
    float v = (SC[d * DD + e] - md * ne - nd * me + sw * md * me) * inv;
    if (d == e) v += JITTER_;
    SC[d * DD + e] = v;
    if (write_out) dout[1 + KC * DD + k * DD * DD + d * DD + e] = v;
  }
  __syncthreads();
  float newm = ne * inv;
  ws[OFF_CUR_M + k * DD + e] = newm;
  if (write_out) dout[1 + k * DD + e] = newm;
  if (accum_diff) {
    float dm = newm - me;
    red[e] = dm * dm;
    __syncthreads();
    for (int s2 = 64; s2 > 0; s2 >>= 1) {
      if (e < s2) red[e] += red[e + s2];
      __syncthreads();
    }
    if (e == 0) atomicAdd(&ws[OFF_DIFFSQ], red[0]);
  }
}

__global__ void k_flag(float* __restrict__ ws) {
  if (threadIdx.x == 0) {
    int* done = (int*)ws + OFF_DONE;
    if (!*done && ws[OFF_DIFFSQ] <= EPS2_) *done = 1;
    ws[OFF_DIFFSQ] = 0.f;
  }
}

__global__ __launch_bounds__(256) void k_lossred(const float* __restrict__ weights,
                                                 float* __restrict__ ws) {
  __shared__ float red[256];
  int k = blockIdx.y, chunk = blockIdx.x, t = threadIdx.x;
  const float* __restrict__ mh = ws + OFF_W + k * NS + chunk * 2048;
  float s = 0.f;
  for (int j = t; j < 2048; j += 256) s += mh[j];
  red[t] = s;
  __syncthreads();
  for (int s2 = 128; s2 > 0; s2 >>= 1) {
    if (t < s2) red[t] += red[t + s2];
    __syncthreads();
  }
  if (t == 0) atomicAdd(&ws[OFF_LOSS], 0.5f * weights[k] * red[0]);
}

__global__ void k_lossfin(const float* __restrict__ weights, const float* __restrict__ ws,
                          float* __restrict__ dout) {
  if (threadIdx.x == 0 && blockIdx.x == 0) {
    float base = 0.f;
    for (int k = 0; k < KC; ++k)
      base += weights[k] * 0.5f * (float)NS * ((float)DD * LOG_2PI_ + ws[OFF_LOGDET + k]);
    dout[0] = base + ws[OFF_LOSS];
  }
}

extern "C" void kernel_launch(void* const* d_in, const int* in_sizes, int n_in,
                              void* d_out, int out_size, void* d_ws, size_t ws_size,
                              hipStream_t stream) {
  const float* x       = (const float*)d_in[0];
  const float* means   = (const float*)d_in[1];
  const float* covs    = (const float*)d_in[2];
  const float* weights = (const float*)d_in[3];
  float* out = (float*)d_out;
  float* ws  = (float*)d_ws;

  hipLaunchKernelGGL(k_init, dim3(256), dim3(256), 0, stream, means, covs, ws);

  // 8 guarded loop iterations + 1 unguarded final update (u==8)
  for (int u = 0; u < 9; ++u) {
    int guarded = (u < 8) ? 1 : 0;
    hipLaunchKernelGGL(k_chol,    dim3(16),      dim3(256), 0, stream, ws, guarded, 0);
    hipLaunchKernelGGL(k_trinv,   dim3(16),      dim3(128), 0, stream, ws, guarded);
    hipLaunchKernelGGL(k_quad,    dim3(128, 16), dim3(256), 0, stream, x, ws, guarded);
    hipLaunchKernelGGL(k_scatter, dim3(32, 16),  dim3(256), 0, stream, x, ws, guarded);
    hipLaunchKernelGGL(k_update,  dim3(16),      dim3(128), 0, stream, ws, out, guarded,
                       (u == 8) ? 1 : 0, guarded);
    if (u < 8) hipLaunchKernelGGL(k_flag, dim3(1), dim3(64), 0, stream, ws);
  }

  // final log-prob: Cholesky of c_fin (+logdet), Linv, mahalanobis, loss
  hipLaunchKernelGGL(k_chol,    dim3(16),      dim3(256), 0, stream, ws, 0, 1);
  hipLaunchKernelGGL(k_trinv,   dim3(16),      dim3(128), 0, stream, ws, 0);
  hipLaunchKernelGGL(k_quad,    dim3(128, 16), dim3(256), 0, stream, x, ws, 0);
  hipLaunchKernelGGL(k_lossred, dim3(8, 16),   dim3(256), 0, stream, weights, ws);
  hipLaunchKernelGGL(k_lossfin, dim3(1),       dim3(64),  0, stream, weights, ws, out);
}

// Round 3
// 2265.863 us; speedup vs baseline: 1.8854x; 1.4023x over previous
//
#include <hip/hip_runtime.h>
#include <math.h>

// GaussianMixtureLayer: EM loop (<=8 iters, device-side convergence flag) +
// final update + Gaussian log-prob loss. Heavy GEMMs on bf16 MFMA with hi/lo
// 3-term split (rel err ~1e-5, vs 2% output tolerance):
//   k_quad   : Y = X Linv^T, w = ||y - t||^2 (+ fused num/sw, fused final loss)
//   k_scatter: S_k = (w.X)^T X  via mfma_f32_32x32x16_bf16, operands streamed
//              from pre-split global bf16 (no LDS, no bank conflicts)
// k_split precomputes Xh/Xl (row-major) and XTh/XTl (transposed) once.

#define NS 16384
#define DD 128
#define KC 16
#define JITTER_ 1e-6f
#define EPS2_ 1e-6f            // (1e-3)^2 Frobenius convergence check
#define LOG_2PI_ 1.8378770664093454f
#define NCHUNK 512             // scatter samples per block

typedef __attribute__((ext_vector_type(8))) short bf16x8;
typedef __attribute__((ext_vector_type(16))) float f32x16;

// workspace float offsets
enum : int {
  OFF_CUR_M  = 0,            // 16*128
  OFF_CS     = 2048,         // 16*128*128 (C, then S accumulator, then new C)
  OFF_LT     = 264192,       // fp32 L^T per k: LT[p][i] = L[i][p]
  OFF_LINVH  = 526336,       // bf16 Linv[d][e] hi  (16*16384 ushort)
  OFF_LINVL  = 657408,       // bf16 Linv lo
  OFF_INVD   = 788480,       // 1/L_ii
  OFF_T      = 790528,       // t_k = Linv_k m_k (fp32)
  OFF_LOGDET = 792576,
  OFF_SW     = 792592,
  OFF_NUM    = 792608,       // 16*128
  OFF_W      = 794656,       // w[k][n]
  OFF_DIFFSQ = 1056800,
  OFF_LOSS   = 1056801,
  OFF_DONE   = 1056802,      // int
  OFF_XH     = 1056804,      // bf16 X[n][e] hi   (NS*DD ushort = 1M floats)
  OFF_XL     = 2105380,
  OFF_XTH    = 3153956,      // bf16 X^T[e][n] hi
  OFF_XTL    = 4202532,
  WS_FLOATS  = 5251108       // ~21 MB
};

__device__ __forceinline__ float bf2f(ushort u) {
  union { unsigned u; float f; } c; c.u = ((unsigned)u) << 16; return c.f;
}
__device__ __forceinline__ ushort f2bf_rne(float f) {
  union { float f; unsigned u; } c; c.f = f;
  unsigned r = c.u + 0x7fffu + ((c.u >> 16) & 1u);
  return (ushort)(r >> 16);
}
__device__ __forceinline__ ushort f2bf_trunc(float f) {
  union { float f; unsigned u; } c; c.f = f; return (ushort)(c.u >> 16);
}

// XOR-quad swizzle for 128x128 LDS matrix (k_chol).
__device__ __forceinline__ int swz(int r, int c) {
  return (r << 7) + ((((c >> 2) + r) & 31) << 2) + (c & 3);
}

__global__ void k_init(const float* __restrict__ means, const float* __restrict__ covs,
                       float* __restrict__ ws) {
  int idx = blockIdx.x * blockDim.x + threadIdx.x;
  for (int i = idx; i < KC * DD * DD; i += gridDim.x * blockDim.x)
    ws[OFF_CS + i] = covs[i];
  if (idx < KC * DD) ws[OFF_CUR_M + idx] = means[idx];
  if (idx == 0) {
    ws[OFF_DIFFSQ] = 0.f;
    ws[OFF_LOSS]   = 0.f;
    ((int*)ws)[OFF_DONE] = 0;
  }
}

// One-time hi/lo bf16 split of X, row-major and transposed. 64 samples/block.
__global__ __launch_bounds__(256) void k_split(const float* __restrict__ x,
                                               float* __restrict__ ws) {
  __shared__ float xt[64 * 132];
  int n0 = blockIdx.x * 64, t = threadIdx.x;
  ushort* __restrict__ XH  = (ushort*)(ws + OFF_XH);
  ushort* __restrict__ XL  = (ushort*)(ws + OFF_XL);
  ushort* __restrict__ XTH = (ushort*)(ws + OFF_XTH);
  ushort* __restrict__ XTL = (ushort*)(ws + OFF_XTL);
  for (int fi = t; fi < 2048; fi += 256) {
    int n = fi >> 5, q = (fi & 31) * 4;
    float4 v = *(const float4*)&x[(size_t)(n0 + n) * DD + q];
    *(float4*)&xt[n * 132 + q] = v;
    ushort4 h, l;
    h.x = f2bf_trunc(v.x); l.x = f2bf_rne(v.x - bf2f(h.x));
    h.y = f2bf_trunc(v.y); l.y = f2bf_rne(v.y - bf2f(h.y));
    h.z = f2bf_trunc(v.z); l.z = f2bf_rne(v.z - bf2f(h.z));
    h.w = f2bf_trunc(v.w); l.w = f2bf_rne(v.w - bf2f(h.w));
    *(ushort4*)&XH[(size_t)(n0 + n) * DD + q] = h;
    *(ushort4*)&XL[(size_t)(n0 + n) * DD + q] = l;
  }
  __syncthreads();
  int e = t >> 1, nh = (t & 1) * 32;
  ushort hs[32], ls[32];
  #pragma unroll
  for (int i = 0; i < 32; ++i) {
    float v = xt[(nh + i) * 132 + e];
    hs[i] = f2bf_trunc(v);
    ls[i] = f2bf_rne(v - bf2f(hs[i]));
  }
  #pragma unroll
  for (int i = 0; i < 32; i += 4) {
    ushort4 hu = make_ushort4(hs[i], hs[i+1], hs[i+2], hs[i+3]);
    ushort4 lu = make_ushort4(ls[i], ls[i+1], ls[i+2], ls[i+3]);
    *(ushort4*)&XTH[(size_t)e * NS + n0 + nh + i] = hu;
    *(ushort4*)&XTL[(size_t)e * NS + n0 + nh + i] = lu;
  }
}

// Blocked right-looking Cholesky of C[k] (from OFF_CS) in LDS (panel=32).
// Writes fp32 LT + 1/diag (+logdet/LOSS-zero on final), zeroes S/num/sw.
__global__ __launch_bounds__(256) void k_chol(float* __restrict__ ws, int guarded, int final_pass) {
  if (guarded && ((const int*)ws)[OFF_DONE]) return;
  __shared__ float m[DD * DD];
  int k = blockIdx.x, t = threadIdx.x;
  float* __restrict__ C = ws + OFF_CS + (size_t)k * DD * DD;
  for (int i = t; i < DD * DD; i += 256) {
    m[swz(i >> 7, i & 127)] = C[i];
    C[i] = 0.f;
  }
  if (t < DD) ws[OFF_NUM + k * DD + t] = 0.f;
  if (t == 0) ws[OFF_SW + k] = 0.f;
  __syncthreads();

  for (int P = 0; P < DD; P += 32) {
    bool rowAct = (t >= P) && (t < DD);
    float r[32];
    if (rowAct) {
      #pragma unroll
      for (int q = 0; q < 8; ++q) {
        float4 v = *(const float4*)&m[swz(t, P + 4 * q)];
        r[4*q+0] = v.x; r[4*q+1] = v.y; r[4*q+2] = v.z; r[4*q+3] = v.w;
      }
    }
    #pragma unroll
    for (int jj = 0; jj < 32; ++jj) {
      int j = P + jj;
      if (t == j) {
        float dsum = 0.f;
        #pragma unroll
        for (int p = 0; p < jj; ++p) dsum += r[p] * r[p];
        r[jj] = sqrtf(r[jj] - dsum);
        #pragma unroll
        for (int q = 0; q < 8; ++q) {
          if (4 * q <= jj)
            *(float4*)&m[swz(j, P + 4 * q)] = make_float4(r[4*q], r[4*q+1], r[4*q+2], r[4*q+3]);
        }
      }
      __syncthreads();
      if (t > j && t < DD) {
        float rj[32];
        #pragma unroll
        for (int q = 0; q < 8; ++q) {
          if (4 * q <= jj) {
            float4 v = *(const float4*)&m[swz(j, P + 4 * q)];
            rj[4*q+0] = v.x; rj[4*q+1] = v.y; rj[4*q+2] = v.z; rj[4*q+3] = v.w;
          }
        }
        float dsum = 0.f;
        #pragma unroll
        for (int p = 0; p < jj; ++p) dsum += r[p] * rj[p];
        r[jj] = (r[jj] - dsum) / rj[jj];
      }
    }
    __syncthreads();
    if (rowAct) {
      #pragma unroll
      for (int q = 0; q < 8; ++q)
        *(float4*)&m[swz(t, P + 4 * q)] = make_float4(r[4*q], r[4*q+1], r[4*q+2], r[4*q+3]);
    }
    __syncthreads();
    int R0 = P + 32;
    if (R0 < DD) {
      int s = DD - R0;
      int tq = R0 + (t & 31);
      for (int b = 0; b < s; b += 32) {
        int q = tq + b;
        float lq[32];
        #pragma unroll
        for (int p4 = 0; p4 < 8; ++p4) {
          float4 v = *(const float4*)&m[swz(q, P + 4 * p4)];
          lq[4*p4+0] = v.x; lq[4*p4+1] = v.y; lq[4*p4+2] = v.z; lq[4*p4+3] = v.w;
        }
        for (int i = R0 + (t >> 5); i < DD; i += 8) {
          float a = m[swz(i, q)];
          #pragma unroll
          for (int p4 = 0; p4 < 8; ++p4) {
            float4 v = *(const float4*)&m[swz(i, P + 4 * p4)];
            a -= v.x * lq[4*p4+0] + v.y * lq[4*p4+1] + v.z * lq[4*p4+2] + v.w * lq[4*p4+3];
          }
          m[swz(i, q)] = a;
        }
      }
    }
    __syncthreads();
  }

  float* __restrict__ LT = ws + OFF_LT + (size_t)k * DD * DD;
  for (int idx = t; idx < DD * DD; idx += 256) {
    int p = idx >> 7, i = idx & 127;
    LT[idx] = (i >= p) ? m[swz(i, p)] : 0.f;
  }
  if (t < DD) ws[OFF_INVD + k * DD + t] = 1.f / m[swz(t, t)];
  if (final_pass && t == 0) {
    float ld = 0.f;
    for (int i = 0; i < DD; ++i) ld += logf(m[swz(i, i)]);
    ws[OFF_LOGDET + k] = 2.f * ld;
    if (k == 0) ws[OFF_LOSS] = 0.f;
  }
}

// Linv = L^{-1}: thread j owns column j. Writes bf16 hi/lo of Linv[d][e]
// (row-major) and fp32 t = Linv m.
__global__ __launch_bounds__(128) void k_trinv(float* __restrict__ ws, int guarded) {
  if (guarded && ((const int*)ws)[OFF_DONE]) return;
  __shared__ float Zs[DD * 129];   // Zs[j][i] = Linv[i][j]
  int k = blockIdx.x, j = threadIdx.x;
  const float* __restrict__ LT   = ws + OFF_LT + (size_t)k * DD * DD;
  const float* __restrict__ invd = ws + OFF_INVD + k * DD;
  float acc[DD];
  #pragma unroll
  for (int i = 0; i < DD; ++i) acc[i] = 0.f;
  #pragma unroll
  for (int p = 0; p < DD; ++p) {
    float zp = ((p == j) ? 1.f : 0.f) - acc[p];
    zp *= invd[p];
    Zs[j * 129 + p] = zp;
    #pragma unroll
    for (int i = p + 1; i < DD; ++i) acc[i] += LT[p * DD + i] * zp;
  }
  __syncthreads();
  ushort* __restrict__ LH = (ushort*)(ws + OFF_LINVH) + (size_t)k * DD * DD;
  ushort* __restrict__ LL = (ushort*)(ws + OFF_LINVL) + (size_t)k * DD * DD;
  for (int idx = j; idx < DD * DD; idx += 128) {
    float v = Zs[(idx & 127) * 129 + (idx >> 7)];   // Linv[d=idx>>7][e=idx&127]
    ushort h = f2bf_trunc(v);
    LH[idx] = h;
    LL[idx] = f2bf_rne(v - bf2f(h));
  }
  const float* __restrict__ mk = ws + OFF_CUR_M + k * DD;
  float s0 = 0.f, s1 = 0.f, s2 = 0.f, s3 = 0.f;
  for (int e = 0; e < DD; e += 4) {
    s0 += Zs[(e + 0) * 129 + j] * mk[e + 0];
    s1 += Zs[(e + 1) * 129 + j] * mk[e + 1];
    s2 += Zs[(e + 2) * 129 + j] * mk[e + 2];
    s3 += Zs[(e + 3) * 129 + j] * mk[e + 3];
  }
  ws[OFF_T + k * DD + j] = (s0 + s1) + (s2 + s3);
}

// w[n,k] = ||X Linv^T - t||^2 via 3-term bf16-split MFMA. Block: 128 samples
// x 128 d, 4 waves (32-sample band each, 4 col-tiles of 32x32x16 MFMA).
// A streamed from Xh/Xl, B from Linv hi/lo (L1-resident). Fused num/sw or
// (final pass) fused weighted loss.
__global__ __launch_bounds__(256) void k_quad(float* __restrict__ ws,
                                              const float* __restrict__ wts,
                                              int guarded, int final_pass) {
  if (guarded && ((const int*)ws)[OFF_DONE]) return;
  __shared__ float warr[128];
  int k = blockIdx.y, n0 = blockIdx.x * 128, t = threadIdx.x;
  int l = t & 63, wv = t >> 6;
  const ushort* __restrict__ XH = (const ushort*)(ws + OFF_XH);
  const ushort* __restrict__ XL = (const ushort*)(ws + OFF_XL);
  const ushort* __restrict__ LH = (const ushort*)(ws + OFF_LINVH) + (size_t)k * DD * DD;
  const ushort* __restrict__ LL = (const ushort*)(ws + OFF_LINVL) + (size_t)k * DD * DD;
  f32x16 acc[4] = {};
  int m  = n0 + 32 * wv + (l & 31);
  int ko = (l >> 5) * 8;
  for (int es = 0; es < DD; es += 16) {
    bf16x8 ah = *(const bf16x8*)&XH[(size_t)m * DD + es + ko];
    bf16x8 al = *(const bf16x8*)&XL[(size_t)m * DD + es + ko];
    #pragma unroll
    for (int c = 0; c < 4; ++c) {
      int d = 32 * c + (l & 31);
      bf16x8 bh = *(const bf16x8*)&LH[(size_t)d * DD + es + ko];
      bf16x8 bl = *(const bf16x8*)&LL[(size_t)d * DD + es + ko];
      acc[c] = __builtin_amdgcn_mfma_f32_32x32x16_bf16(ah, bh, acc[c], 0, 0, 0);
      acc[c] = __builtin_amdgcn_mfma_f32_32x32x16_bf16(ah, bl, acc[c], 0, 0, 0);
      acc[c] = __builtin_amdgcn_mfma_f32_32x32x16_bf16(al, bh, acc[c], 0, 0, 0);
    }
  }
  // epilogue: w per sample row = sum_d (y - t)^2
  float tv[4];
  #pragma unroll
  for (int c = 0; c < 4; ++c) tv[c] = ws[OFF_T + k * DD + 32 * c + (l & 31)];
  float part[16];
  #pragma unroll
  for (int r = 0; r < 16; ++r) {
    float s = 0.f;
    #pragma unroll
    for (int c = 0; c < 4; ++c) { float d = acc[c][r] - tv[c]; s += d * d; }
    part[r] = s;
  }
  #pragma unroll
  for (int mk2 = 1; mk2 < 32; mk2 <<= 1)
    #pragma unroll
    for (int r = 0; r < 16; ++r) part[r] += __shfl_xor(part[r], mk2, 64);
  int h = l >> 5;
  if ((l & 31) < 16) {
    int r = l & 31;
    int row = (r & 3) + 8 * (r >> 2) + 4 * h + 32 * wv;   // C/D layout m74/m101
    warr[row] = part[r];
    ws[OFF_W + k * NS + n0 + row] = part[r];
  }
  __syncthreads();
  if (!final_pass) {
    if (t < 128) {
      float s = 0.f;
      for (int n = 0; n < 128; ++n) {
        float xv = bf2f(XH[(size_t)(n0 + n) * DD + t]) + bf2f(XL[(size_t)(n0 + n) * DD + t]);
        s += warr[n] * xv;
      }
      atomicAdd(&ws[OFF_NUM + k * DD + t], s);
    } else if (t == 128) {
      float s = 0.f;
      for (int n = 0; n < 128; ++n) s += warr[n];
      atomicAdd(&ws[OFF_SW + k], s);
    }
  } else {
    if (t < 64) {
      float s = warr[t] + warr[t + 64];
      #pragma unroll
      for (int mk2 = 1; mk2 < 64; mk2 <<= 1) s += __shfl_xor(s, mk2, 64);
      if (t == 0) atomicAdd(&ws[OFF_LOSS], 0.5f * wts[k] * s);
    }
  }
}

// S_k += (w.X)^T X over NCHUNK samples via 3-term bf16-split MFMA.
// A = (w.X)^T built on the fly from XT hi/lo + w; B = XT hi/lo direct.
// No LDS. Epilogue: fp32 atomics into S (16 MB total vs old 262 MB).
__global__ __launch_bounds__(256) void k_scatter(float* __restrict__ ws, int guarded) {
  if (guarded && ((const int*)ws)[OFF_DONE]) return;
  int k = blockIdx.y, c0 = blockIdx.x * NCHUNK, t = threadIdx.x;
  int l = t & 63, wv = t >> 6;
  const ushort* __restrict__ XTH = (const ushort*)(ws + OFF_XTH);
  const ushort* __restrict__ XTL = (const ushort*)(ws + OFF_XTL);
  const float* __restrict__ wp = ws + OFF_W + k * NS + c0;
  f32x16 acc[4] = {};
  int d  = 32 * wv + (l & 31);
  int ko = (l >> 5) * 8;
  for (int ns = 0; ns < NCHUNK; ns += 16) {
    bf16x8 th = *(const bf16x8*)&XTH[(size_t)d * NS + c0 + ns + ko];
    bf16x8 tl = *(const bf16x8*)&XTL[(size_t)d * NS + c0 + ns + ko];
    float4 w0 = *(const float4*)&wp[ns + ko];
    float4 w1 = *(const float4*)&wp[ns + ko + 4];
    float wj[8] = {w0.x, w0.y, w0.z, w0.w, w1.x, w1.y, w1.z, w1.w};
    bf16x8 ah, al;
    #pragma unroll
    for (int j = 0; j < 8; ++j) {
      float xf = bf2f((ushort)th[j]) + bf2f((ushort)tl[j]);
      float zf = wj[j] * xf;
      union { float f; unsigned u; } cz; cz.f = zf;
      ah[j] = (short)(ushort)(cz.u >> 16);
      union { unsigned u; float f; } ch; ch.u = cz.u & 0xffff0000u;
      al[j] = (short)f2bf_rne(zf - ch.f);
    }
    #pragma unroll
    for (int c = 0; c < 4; ++c) {
      int e = 32 * c + (l & 31);
      bf16x8 bh = *(const bf16x8*)&XTH[(size_t)e * NS + c0 + ns + ko];
      bf16x8 bl = *(const bf16x8*)&XTL[(size_t)e * NS + c0 + ns + ko];
      acc[c] = __builtin_amdgcn_mfma_f32_32x32x16_bf16(ah, bh, acc[c], 0, 0, 0);
      acc[c] = __builtin_amdgcn_mfma_f32_32x32x16_bf16(ah, bl, acc[c], 0, 0, 0);
      acc[c] = __builtin_amdgcn_mfma_f32_32x32x16_bf16(al, bh, acc[c], 0, 0, 0);
    }
  }
  float* __restrict__ S = ws + OFF_CS + (size_t)k * DD * DD;
  int h = l >> 5;
  #pragma unroll
  for (int c = 0; c < 4; ++c) {
    int e = 32 * c + (l & 31);
    #pragma unroll
    for (int r = 0; r < 16; ++r) {
      int drow = 32 * wv + (r & 3) + 8 * (r >> 2) + 4 * h;
      atomicAdd(&S[drow * DD + e], acc[c][r]);
    }
  }
}

// new_m = num/sw; new_C = (S - m num^T - num m^T + sw m m^T)/sw + jitter*I.
__global__ __launch_bounds__(128) void k_update(float* __restrict__ ws, float* __restrict__ dout,
                                                int guarded, int write_out, int accum_diff) {
  if (guarded && ((const int*)ws)[OFF_DONE]) return;
  __shared__ float red[128];
  int k = blockIdx.x, e = threadIdx.x;
  float sw = ws[OFF_SW + k];
  float inv = 1.f / sw;
  float me = ws[OFF_CUR_M + k * DD + e];
  float ne = ws[OFF_NUM + k * DD + e];
  float* __restrict__ SC = ws + OFF_CS + (size_t)k * DD * DD;
  const float* __restrict__ cm = ws + OFF_CUR_M + k * DD;
  const float* __restrict__ nm = ws + OFF_NUM + k * DD;
  for (int d = 0; d < DD; ++d) {
    float md = cm[d];
    float nd = nm[d];
    float v = (SC[d * DD + e] - md * ne - nd * me + sw * md * me) * inv;
    if (d == e) v += JITTER_;
    SC[d * DD + e] = v;
    if (write_out) dout[1 + KC * DD + k * DD * DD + d * DD + e] = v;
  }
  __syncthreads();
  float newm = ne * inv;
  ws[OFF_CUR_M + k * DD + e] = newm;
  if (write_out) dout[1 + k * DD + e] = newm;
  if (accum_diff) {
    float dm = newm - me;
    red[e] = dm * dm;
    __syncthreads();
    for (int s2 = 64; s2 > 0; s2 >>= 1) {
      if (e < s2) red[e] += red[e + s2];
      __syncthreads();
    }
    if (e == 0) atomicAdd(&ws[OFF_DIFFSQ], red[0]);
  }
}

__global__ void k_flag(float* __restrict__ ws) {
  if (threadIdx.x == 0) {
    int* done = (int*)ws + OFF_DONE;
    if (!*done && ws[OFF_DIFFSQ] <= EPS2_) *done = 1;
    ws[OFF_DIFFSQ] = 0.f;
  }
}

__global__ void k_lossfin(const float* __restrict__ weights, const float* __restrict__ ws,
                          float* __restrict__ dout) {
  if (threadIdx.x == 0 && blockIdx.x == 0) {
    float base = 0.f;
    for (int k = 0; k < KC; ++k)
      base += weights[k] * 0.5f * (float)NS * ((float)DD * LOG_2PI_ + ws[OFF_LOGDET + k]);
    dout[0] = base + ws[OFF_LOSS];
  }
}

extern "C" void kernel_launch(void* const* d_in, const int* in_sizes, int n_in,
                              void* d_out, int out_size, void* d_ws, size_t ws_size,
                              hipStream_t stream) {
  const float* x       = (const float*)d_in[0];
  const float* means   = (const float*)d_in[1];
  const float* covs    = (const float*)d_in[2];
  const float* weights = (const float*)d_in[3];
  float* out = (float*)d_out;
  float* ws  = (float*)d_ws;

  hipLaunchKernelGGL(k_init,  dim3(256), dim3(256), 0, stream, means, covs, ws);
  hipLaunchKernelGGL(k_split, dim3(NS / 64), dim3(256), 0, stream, x, ws);

  // 8 guarded loop iterations + 1 unguarded final update (u==8)
  for (int u = 0; u < 9; ++u) {
    int guarded = (u < 8) ? 1 : 0;
    hipLaunchKernelGGL(k_chol,    dim3(16),      dim3(256), 0, stream, ws, guarded, 0);
    hipLaunchKernelGGL(k_trinv,   dim3(16),      dim3(128), 0, stream, ws, guarded);
    hipLaunchKernelGGL(k_quad,    dim3(128, 16), dim3(256), 0, stream, ws, weights, guarded, 0);
    hipLaunchKernelGGL(k_scatter, dim3(NS / NCHUNK, 16), dim3(256), 0, stream, ws, guarded);
    hipLaunchKernelGGL(k_update,  dim3(16),      dim3(128), 0, stream, ws, out, guarded,
                       (u == 8) ? 1 : 0, guarded);
    if (u < 8) hipLaunchKernelGGL(k_flag, dim3(1), dim3(64), 0, stream, ws);
  }

  // final log-prob: Cholesky of c_fin (+logdet), Linv, mahalanobis+loss
  hipLaunchKernelGGL(k_chol,    dim3(16),      dim3(256), 0, stream, ws, 0, 1);
  hipLaunchKernelGGL(k_trinv,   dim3(16),      dim3(128), 0, stream, ws, 0);
  hipLaunchKernelGGL(k_quad,    dim3(128, 16), dim3(256), 0, stream, ws, weights, 0, 1);
  hipLaunchKernelGGL(k_lossfin, dim3(1),       dim3(64),  0, stream, weights, ws, out);
}